// Round 3
// baseline (1655.915 us; speedup 1.0000x reference)
//
#include <hip/hip_runtime.h>
#include <hip/hip_bf16.h>
#include <math.h>

typedef __hip_bfloat16 bf16;

#define NRAYS 4096
#define NSAMP 256
#define RESG  128
#define RS2   16384      // 128*128 (x stride)
#define RS3   2097152    // 128^3   (channel stride)
#define ACT_SHIFT (-4.59511985013459f)

// ---- ws float offsets ----
#define OW0   0        // W0T[64][54]
#define OB0   3456
#define OW1   3520     // W1T[64][64]
#define OB1   7616
#define OW2   7680     // W2T[64][64]
#define OB2   11776
#define OW3   11840    // W3T[3][64]
#define OB3   12032
#define OFLAG 12035    // 1.0f if inputs are float32, 0.0f if bf16
#define ORO   12036    // rays_o fp32 [4096*3]
#define ORD   24324    // rays_d normalized fp32 [4096*3]
#define OVD   36612    // viewdirs normalized fp32 [4096*3]

__device__ __forceinline__ float ldT(const float* p, int i){ return p[i]; }
__device__ __forceinline__ float ldT(const bf16*  p, int i){ return __bfloat162float(p[i]); }

template<typename T>
__device__ void fill_ws(const void* W0,const void* b0,const void* W1,const void* b1,
                        const void* W2,const void* b2,const void* W3,const void* b3,
                        const void* ro,const void* rd,const void* vd,
                        float* __restrict__ wb, int tid)
{
  const T* tW0=(const T*)W0; const T* tb0=(const T*)b0;
  const T* tW1=(const T*)W1; const T* tb1=(const T*)b1;
  const T* tW2=(const T*)W2; const T* tb2=(const T*)b2;
  const T* tW3=(const T*)W3; const T* tb3=(const T*)b3;
  const T* tro=(const T*)ro; const T* trd=(const T*)rd; const T* tvd=(const T*)vd;

  for (int idx = tid; idx < 3456; idx += 256){ int j = idx/54, k = idx - j*54; wb[OW0+idx] = ldT(tW0, k*64+j); }
  for (int idx = tid; idx < 64;   idx += 256) wb[OB0+idx] = ldT(tb0, idx);
  for (int idx = tid; idx < 4096; idx += 256){ int j = idx>>6, k = idx&63; wb[OW1+idx] = ldT(tW1, k*64+j); }
  for (int idx = tid; idx < 64;   idx += 256) wb[OB1+idx] = ldT(tb1, idx);
  for (int idx = tid; idx < 4096; idx += 256){ int j = idx>>6, k = idx&63; wb[OW2+idx] = ldT(tW2, k*64+j); }
  for (int idx = tid; idx < 64;   idx += 256) wb[OB2+idx] = ldT(tb2, idx);
  for (int idx = tid; idx < 192;  idx += 256){ int j = idx>>6, k = idx&63; wb[OW3+idx] = ldT(tW3, k*3+j); }
  if (tid < 3) wb[OB3+tid] = ldT(tb3, tid);

  for (int r = tid; r < NRAYS; r += 256){
    float ox = ldT(tro, r*3+0), oy = ldT(tro, r*3+1), oz = ldT(tro, r*3+2);
    wb[ORO+r*3+0]=ox; wb[ORO+r*3+1]=oy; wb[ORO+r*3+2]=oz;
    float dx = ldT(trd, r*3+0), dy = ldT(trd, r*3+1), dz = ldT(trd, r*3+2);
    float dn = 1.0f / sqrtf(dx*dx+dy*dy+dz*dz);
    wb[ORD+r*3+0]=dx*dn; wb[ORD+r*3+1]=dy*dn; wb[ORD+r*3+2]=dz*dn;
    float vx = ldT(tvd, r*3+0), vy = ldT(tvd, r*3+1), vz = ldT(tvd, r*3+2);
    float vn = 1.0f / sqrtf(vx*vx+vy*vy+vz*vz);
    wb[OVD+r*3+0]=vx*vn; wb[OVD+r*3+1]=vy*vn; wb[OVD+r*3+2]=vz*vn;
  }
}

// Detect input dtype (insurance) + convert weights/rays to fp32 workspace.
// W1 ~ N(0,1)*0.1: as genuine bf16 every |val| < 1. If the buffer is really
// float32, bf16-reinterpreted halves have random exponent bits -> huge/NaN
// values with near-certainty over 512 probes.
__global__ void prep(const void* W0,const void* b0,const void* W1,const void* b1,
                     const void* W2,const void* b2,const void* W3,const void* b3,
                     const void* ro,const void* rd,const void* vd,
                     float* __restrict__ wb)
{
  __shared__ int s_f32;
  const int tid = threadIdx.x;
  if (tid == 0) s_f32 = 0;
  __syncthreads();
  {
    const bf16* t1 = (const bf16*)W1;
    float a = fabsf(__bfloat162float(t1[2*tid]));
    float b = fabsf(__bfloat162float(t1[2*tid+1]));
    if (!(a < 100.0f) || !(b < 100.0f)) atomicOr(&s_f32, 1);
  }
  __syncthreads();
  const bool isf32 = (s_f32 != 0);
  if (tid == 0) wb[OFLAG] = isf32 ? 1.0f : 0.0f;
  if (isf32) fill_ws<float>(W0,b0,W1,b1,W2,b2,W3,b3,ro,rd,vd,wb,tid);
  else       fill_ws<bf16 >(W0,b0,W1,b1,W2,b2,W3,b3,ro,rd,vd,wb,tid);
}

// ---- render body: one block per ray, one thread per sample ----
template<typename GT>
__device__ __forceinline__ void render_body(const GT* __restrict__ latent,
                                            const GT* __restrict__ normals,
                                            const float* __restrict__ wb,
                                            float* __restrict__ out)
{
  const int ray = blockIdx.x;
  const int i   = threadIdx.x;

  const float ox = wb[ORO+ray*3+0], oy = wb[ORO+ray*3+1], oz = wb[ORO+ray*3+2];
  const float dx = wb[ORD+ray*3+0], dy = wb[ORD+ray*3+1], dz = wb[ORD+ray*3+2];
  const float vx = wb[OVD+ray*3+0], vy = wb[OVD+ray*3+1], vz = wb[OVD+ray*3+2];

  const float t  = 0.2f + (2.8f/255.0f) * (float)i;
  const float px = ox + dx*t, py = oy + dy*t, pz = oz + dz*t;
  const bool inb = (px >= -1.0f) & (px <= 1.0f) & (py >= -1.0f) & (py <= 1.0f)
                 & (pz >= -1.0f) & (pz <= 1.0f);

  float alpha = 0.0f, nx = 0.0f, ny = 0.0f, nz = 0.0f;
  float r0 = 0.0f, r1 = 0.0f, r2 = 0.0f;

  if (inb) {
    float ux = fminf(fmaxf((px+1.0f)*0.5f, 0.0f), 1.0f) * 127.0f;
    float uy = fminf(fmaxf((py+1.0f)*0.5f, 0.0f), 1.0f) * 127.0f;
    float uz = fminf(fmaxf((pz+1.0f)*0.5f, 0.0f), 1.0f) * 127.0f;
    int x0 = (int)floorf(ux); x0 = x0 > 126 ? 126 : (x0 < 0 ? 0 : x0);
    int y0 = (int)floorf(uy); y0 = y0 > 126 ? 126 : (y0 < 0 ? 0 : y0);
    int z0 = (int)floorf(uz); z0 = z0 > 126 ? 126 : (z0 < 0 ? 0 : z0);
    float fx = ux - (float)x0, fy = uy - (float)y0, fz = uz - (float)z0;
    const int base = x0*RS2 + y0*RESG + z0;
    const float gx = 1.0f - fx, gy = 1.0f - fy, gz = 1.0f - fz;
    const float w000 = gx*gy*gz, w100 = fx*gy*gz, w010 = gx*fy*gz, w001 = gx*gy*fz;
    const float w110 = fx*fy*gz, w101 = fx*gy*fz, w011 = gx*fy*fz, w111 = fx*fy*fz;

    float ch[19];
#pragma unroll
    for (int c = 0; c < 19; c++){
      const GT* g = (c < 16 ? latent + c*RS3 : normals + (c-16)*RS3) + base;
      ch[c] = w000*ldT(g,0)        + w100*ldT(g,RS2)
            + w010*ldT(g,RESG)     + w001*ldT(g,1)
            + w110*ldT(g,RS2+RESG) + w101*ldT(g,RS2+1)
            + w011*ldT(g,RESG+1)   + w111*ldT(g,RS2+RESG+1);
    }

    float xs = ch[0] + ACT_SHIFT;
    float sp = xs > 15.0f ? xs : log1pf(__expf(xs));
    alpha = 1.0f - __expf(-sp * 0.5f);

    float nn  = sqrtf(ch[16]*ch[16] + ch[17]*ch[17] + ch[18]*ch[18]);
    float ninv = 1.0f / fmaxf(nn, 1e-12f);
    nx = ch[16]*ninv; ny = ch[17]*ninv; nz = ch[18]*ninv;

    float dt = -(vx*nx + vy*ny + vz*nz);
    float rx = 2.0f*dt*nx + vx, ry = 2.0f*dt*ny + vy, rz = 2.0f*dt*nz + vz;

    float feat[54];
#pragma unroll
    for (int k = 0; k < 15; k++) feat[k] = ch[k+1];
    feat[15] = rx; feat[16] = ry; feat[17] = rz;
#pragma unroll
    for (int f = 0; f < 6; f++){
      float s = (float)(1 << f);
      feat[18 + f*3 + 0] = __sinf(rx*s);
      feat[18 + f*3 + 1] = __sinf(ry*s);
      feat[18 + f*3 + 2] = __sinf(rz*s);
      feat[36 + f*3 + 0] = __cosf(rx*s);
      feat[36 + f*3 + 1] = __cosf(ry*s);
      feat[36 + f*3 + 2] = __cosf(rz*s);
    }

    float h1[64];
#pragma unroll
    for (int j = 0; j < 64; j++){
      float s = wb[OB0+j];
#pragma unroll
      for (int k = 0; k < 54; k++) s += feat[k] * wb[OW0 + j*54 + k];
      h1[j] = fmaxf(s, 0.0f);
    }
    float h2[64];
#pragma unroll
    for (int j = 0; j < 64; j++){
      float s = wb[OB1+j];
#pragma unroll
      for (int k = 0; k < 64; k++) s += h1[k] * wb[OW1 + j*64 + k];
      h2[j] = fmaxf(s, 0.0f);
    }
    float h3[64];
#pragma unroll
    for (int j = 0; j < 64; j++){
      float s = wb[OB2+j];
#pragma unroll
      for (int k = 0; k < 64; k++) s += h2[k] * wb[OW2 + j*64 + k];
      h3[j] = fmaxf(s, 0.0f);
    }
    float o_[3];
#pragma unroll
    for (int j = 0; j < 3; j++){
      float s = wb[OB3+j];
#pragma unroll
      for (int k = 0; k < 64; k++) s += h3[k] * wb[OW3 + j*64 + k];
      o_[j] = 1.0f / (1.0f + __expf(-s));
    }
    r0 = o_[0]; r1 = o_[1]; r2 = o_[2];
  }

  __shared__ float sh_alpha[NSAMP];
  __shared__ float sh_ainv[NSAMP+1];
  __shared__ float sh_red[4][8];
  sh_alpha[i] = alpha;
  __syncthreads();
  if (i == 0){
    float cum = 1.0f;
    sh_ainv[0] = 1.0f;
    for (int k = 0; k < NSAMP; k++){
      cum *= fmaxf(1.0f - sh_alpha[k], 1e-10f);
      sh_ainv[k+1] = cum;
    }
  }
  __syncthreads();

  const float av = sh_ainv[i];
  const float w  = alpha * av;

  // per-sample outputs (fp32!)
  float* outw = out + 36864;            // weights      (4096*256)
  float* outa = out + 36864 + 1048576;  // alphainv_cum (4096*257)
  outw[ray*NSAMP + i] = w;
  outa[ray*(NSAMP+1) + i] = av;
  if (i == NSAMP-1) outa[ray*(NSAMP+1) + NSAMP] = sh_ainv[NSAMP];

  float vals[8] = { w*r0, w*r1, w*r2, w*t, w, w*nx, w*ny, w*nz };
#pragma unroll
  for (int v = 0; v < 8; v++){
    float x = vals[v];
#pragma unroll
    for (int m = 32; m > 0; m >>= 1) x += __shfl_xor(x, m, 64);
    if ((i & 63) == 0) sh_red[i >> 6][v] = x;
  }
  __syncthreads();
  if (i == 0){
    const float last = sh_ainv[NSAMP];
    float s[8];
#pragma unroll
    for (int v = 0; v < 8; v++) s[v] = sh_red[0][v] + sh_red[1][v] + sh_red[2][v] + sh_red[3][v];
    const float dm = s[3] + last * 3.0f;
    out[ray*3+0] = s[0] + last;                 // rgb_marched (+BG*last, BG=1)
    out[ray*3+1] = s[1] + last;
    out[ray*3+2] = s[2] + last;
    float* o1 = out + 12288; o1[ray] = dm;          // depth_marched
    float* o2 = out + 16384; o2[ray] = 1.0f / dm;   // disp
    float* o3 = out + 20480; o3[ray] = s[4];        // acc
    float* o4 = out + 24576;                         // normals_marched
    o4[ray*3+0] = s[5]; o4[ray*3+1] = s[6]; o4[ray*3+2] = s[7];
  }
}

__global__ __launch_bounds__(256)
void render_kernel(const void* __restrict__ latent, const void* __restrict__ normals,
                   const float* __restrict__ wb, float* __restrict__ out)
{
  if (wb[OFLAG] > 0.5f)
    render_body<float>((const float*)latent, (const float*)normals, wb, out);
  else
    render_body<bf16 >((const bf16*)latent,  (const bf16*)normals,  wb, out);
}

extern "C" void kernel_launch(void* const* d_in, const int* in_sizes, int n_in,
                              void* d_out, int out_size, void* d_ws, size_t ws_size,
                              hipStream_t stream)
{
  float* wb = (float*)d_ws;
  prep<<<1, 256, 0, stream>>>(d_in[5], d_in[6], d_in[7], d_in[8],
                              d_in[9], d_in[10], d_in[11], d_in[12],
                              d_in[0], d_in[1], d_in[2], wb);
  render_kernel<<<NRAYS, 256, 0, stream>>>(d_in[3], d_in[4], wb, (float*)d_out);
}

// Round 4
// 479.939 us; speedup vs baseline: 3.4503x; 3.4503x over previous
//
#include <hip/hip_runtime.h>
#include <hip/hip_bf16.h>
#include <math.h>

typedef __hip_bfloat16 bf16;
typedef float f32x4 __attribute__((ext_vector_type(4)));
typedef short short8 __attribute__((ext_vector_type(8)));

#define NRAYS 4096
#define NSAMP 256
#define RESG  128
#define RS2   16384      // 128*128 (x stride)
#define RS3   2097152    // 128^3   (channel stride)
#define ACT_SHIFT (-4.59511985013459f)

// ---- ws layout ----
// floats:
#define OFLAG 0
#define OBIAS 16        // b0@16, b1@80, b2@144, b3(16 padded)@224
#define ORO   272       // rays_o fp32 [4096*3]
#define ORD   12560     // rays_d normalized
#define OVD   24848     // viewdirs normalized
// bf16 B-fragments at byte offset 148544 (16B aligned):
//   L0@0, L1@4096, L2@8192, L3@12288 (ushort offsets); frag idx = ((nt*2+ks)*64+lane)*8+j
#define FRAG_BYTE_OFF 148544

__device__ __forceinline__ float ldT(const float* p, int i){ return p[i]; }
__device__ __forceinline__ float ldT(const bf16*  p, int i){ return __bfloat162float(p[i]); }

// RNE float->bf16 bit pattern
__device__ __forceinline__ unsigned short f2bu(float f){
  unsigned int x = __float_as_uint(f);
  unsigned int r = (x + 0x7FFFu + ((x >> 16) & 1u)) >> 16;
  return (unsigned short)r;
}

template<typename T>
__device__ void fill_ws(const void* W0,const void* b0,const void* W1,const void* b1,
                        const void* W2,const void* b2,const void* W3,const void* b3,
                        const void* ro,const void* rd,const void* vd,
                        float* __restrict__ wb, int tid)
{
  const T* tW0=(const T*)W0; const T* tb0=(const T*)b0;
  const T* tW1=(const T*)W1; const T* tb1=(const T*)b1;
  const T* tW2=(const T*)W2; const T* tb2=(const T*)b2;
  const T* tW3=(const T*)W3; const T* tb3=(const T*)b3;
  const T* tro=(const T*)ro; const T* trd=(const T*)rd; const T* tvd=(const T*)vd;

  // biases
  for (int idx = tid; idx < 64; idx += 256){
    wb[16+idx]  = ldT(tb0, idx);
    wb[80+idx]  = ldT(tb1, idx);
    wb[144+idx] = ldT(tb2, idx);
  }
  if (tid < 16) wb[224+tid] = (tid < 3) ? ldT(tb3, tid) : 0.0f;

  // rays
  for (int r = tid; r < NRAYS; r += 256){
    float ox = ldT(tro, r*3+0), oy = ldT(tro, r*3+1), oz = ldT(tro, r*3+2);
    wb[ORO+r*3+0]=ox; wb[ORO+r*3+1]=oy; wb[ORO+r*3+2]=oz;
    float dx = ldT(trd, r*3+0), dy = ldT(trd, r*3+1), dz = ldT(trd, r*3+2);
    float dn = 1.0f / sqrtf(dx*dx+dy*dy+dz*dz);
    wb[ORD+r*3+0]=dx*dn; wb[ORD+r*3+1]=dy*dn; wb[ORD+r*3+2]=dz*dn;
    float vx = ldT(tvd, r*3+0), vy = ldT(tvd, r*3+1), vz = ldT(tvd, r*3+2);
    float vn = 1.0f / sqrtf(vx*vx+vy*vy+vz*vz);
    wb[OVD+r*3+0]=vx*vn; wb[OVD+r*3+1]=vy*vn; wb[OVD+r*3+2]=vz*vn;
  }

  // B-fragments (bf16). mfma_f32_16x16x32_bf16 B layout:
  //   lane holds B[k = ks*32 + (lane>>4)*8 + j][n = nt*16 + (lane&15)]
  unsigned short* fu = (unsigned short*)((char*)wb + FRAG_BYTE_OFF);
  // layer 0: W0 (54,64), K padded to 64
  for (int idx = tid; idx < 4096; idx += 256){
    int blk = idx >> 9, rem = idx & 511, lane = rem >> 3, j = rem & 7;
    int nt = blk >> 1, ks = blk & 1;
    int k = ks*32 + ((lane>>4)<<3) + j, n = nt*16 + (lane & 15);
    float v = (k < 54) ? ldT(tW0, k*64 + n) : 0.0f;
    fu[idx] = f2bu(v);
  }
  // layers 1,2: (64,64)
  for (int idx = tid; idx < 4096; idx += 256){
    int blk = idx >> 9, rem = idx & 511, lane = rem >> 3, j = rem & 7;
    int nt = blk >> 1, ks = blk & 1;
    int k = ks*32 + ((lane>>4)<<3) + j, n = nt*16 + (lane & 15);
    fu[4096+idx] = f2bu(ldT(tW1, k*64 + n));
    fu[8192+idx] = f2bu(ldT(tW2, k*64 + n));
  }
  // layer 3: W3 (64,3), N padded to 16, single n-tile
  for (int idx = tid; idx < 1024; idx += 256){
    int blk = idx >> 9, rem = idx & 511, lane = rem >> 3, j = rem & 7;
    int ks = blk;
    int k = ks*32 + ((lane>>4)<<3) + j, n = lane & 15;
    float v = (n < 3) ? ldT(tW3, k*3 + n) : 0.0f;
    fu[12288+idx] = f2bu(v);
  }
}

__global__ void prep(const void* W0,const void* b0,const void* W1,const void* b1,
                     const void* W2,const void* b2,const void* W3,const void* b3,
                     const void* ro,const void* rd,const void* vd,
                     float* __restrict__ wb)
{
  __shared__ int s_f32;
  const int tid = threadIdx.x;
  if (tid == 0) s_f32 = 0;
  __syncthreads();
  {
    const bf16* t1 = (const bf16*)W1;
    float a = fabsf(__bfloat162float(t1[2*tid]));
    float b = fabsf(__bfloat162float(t1[2*tid+1]));
    if (!(a < 100.0f) || !(b < 100.0f)) atomicOr(&s_f32, 1);
  }
  __syncthreads();
  const bool isf32 = (s_f32 != 0);
  if (tid == 0) wb[OFLAG] = isf32 ? 1.0f : 0.0f;
  if (isf32) fill_ws<float>(W0,b0,W1,b1,W2,b2,W3,b3,ro,rd,vd,wb,tid);
  else       fill_ws<bf16 >(W0,b0,W1,b1,W2,b2,W3,b3,ro,rd,vd,wb,tid);
}

// ---- render: one block per ray, thread i = sample i; MLP via per-wave MFMA GEMM ----
template<typename GT>
__device__ __forceinline__ void render_body(const GT* __restrict__ latent,
                                            const GT* __restrict__ normals,
                                            const float* __restrict__ wb,
                                            float* __restrict__ out)
{
  const int ray  = blockIdx.x;
  const int i    = threadIdx.x;
  const int lane = i & 63;
  const int wv   = i >> 6;
  const int quad = lane >> 4;
  const int n15  = lane & 15;
  const int wbase = wv * 64;

  __shared__ unsigned short act[NSAMP*72];   // activations, row stride 72 bf16 (144B)
  __shared__ float sh_w[NSAMP];
  __shared__ float sh_wt[4];
  __shared__ float red[4][8];
  __shared__ float red_rgb[4][16];

  const float ox = wb[ORO+ray*3+0], oy = wb[ORO+ray*3+1], oz = wb[ORO+ray*3+2];
  const float dx = wb[ORD+ray*3+0], dy = wb[ORD+ray*3+1], dz = wb[ORD+ray*3+2];
  const float vx = wb[OVD+ray*3+0], vy = wb[OVD+ray*3+1], vz = wb[OVD+ray*3+2];

  const float t  = 0.2f + (2.8f/255.0f) * (float)i;
  const float px = ox + dx*t, py = oy + dy*t, pz = oz + dz*t;
  const bool inb = (px >= -1.0f) & (px <= 1.0f) & (py >= -1.0f) & (py <= 1.0f)
                 & (pz >= -1.0f) & (pz <= 1.0f);

  float alpha = 0.0f, nx = 0.0f, ny = 0.0f, nz = 0.0f;
  float fv[64];
#pragma unroll
  for (int k = 0; k < 64; k++) fv[k] = 0.0f;

  if (inb) {
    float ux = fminf(fmaxf((px+1.0f)*0.5f, 0.0f), 1.0f) * 127.0f;
    float uy = fminf(fmaxf((py+1.0f)*0.5f, 0.0f), 1.0f) * 127.0f;
    float uz = fminf(fmaxf((pz+1.0f)*0.5f, 0.0f), 1.0f) * 127.0f;
    int x0 = (int)floorf(ux); x0 = x0 > 126 ? 126 : (x0 < 0 ? 0 : x0);
    int y0 = (int)floorf(uy); y0 = y0 > 126 ? 126 : (y0 < 0 ? 0 : y0);
    int z0 = (int)floorf(uz); z0 = z0 > 126 ? 126 : (z0 < 0 ? 0 : z0);
    float fx = ux - (float)x0, fy = uy - (float)y0, fz = uz - (float)z0;
    const int base = x0*RS2 + y0*RESG + z0;
    const float gx = 1.0f - fx, gy = 1.0f - fy, gz = 1.0f - fz;
    const float w000 = gx*gy*gz, w100 = fx*gy*gz, w010 = gx*fy*gz, w001 = gx*gy*fz;
    const float w110 = fx*fy*gz, w101 = fx*gy*fz, w011 = gx*fy*fz, w111 = fx*fy*fz;

    float ch[19];
#pragma unroll
    for (int c = 0; c < 19; c++){
      const GT* g = (c < 16 ? latent + c*RS3 : normals + (c-16)*RS3) + base;
      ch[c] = w000*ldT(g,0)        + w100*ldT(g,RS2)
            + w010*ldT(g,RESG)     + w001*ldT(g,1)
            + w110*ldT(g,RS2+RESG) + w101*ldT(g,RS2+1)
            + w011*ldT(g,RESG+1)   + w111*ldT(g,RS2+RESG+1);
    }

    float xs = ch[0] + ACT_SHIFT;
    float sp = xs > 15.0f ? xs : log1pf(__expf(xs));
    alpha = 1.0f - __expf(-sp * 0.5f);

    float nn  = sqrtf(ch[16]*ch[16] + ch[17]*ch[17] + ch[18]*ch[18]);
    float ninv = 1.0f / fmaxf(nn, 1e-12f);
    nx = ch[16]*ninv; ny = ch[17]*ninv; nz = ch[18]*ninv;

    float dt = -(vx*nx + vy*ny + vz*nz);
    float rx = 2.0f*dt*nx + vx, ry = 2.0f*dt*ny + vy, rz = 2.0f*dt*nz + vz;

#pragma unroll
    for (int k = 0; k < 15; k++) fv[k] = ch[k+1];
    fv[15] = rx; fv[16] = ry; fv[17] = rz;
#pragma unroll
    for (int f = 0; f < 6; f++){
      float s = (float)(1 << f);
      fv[18 + f*3 + 0] = __sinf(rx*s);
      fv[18 + f*3 + 1] = __sinf(ry*s);
      fv[18 + f*3 + 2] = __sinf(rz*s);
      fv[36 + f*3 + 0] = __cosf(rx*s);
      fv[36 + f*3 + 1] = __cosf(ry*s);
      fv[36 + f*3 + 2] = __cosf(rz*s);
    }
  }

  // pack feat -> LDS row i (bf16), 8x 16B writes
#pragma unroll
  for (int c = 0; c < 8; c++){
    short8 v;
#pragma unroll
    for (int k = 0; k < 8; k++) v[k] = (short)f2bu(fv[c*8+k]);
    *(short8*)&act[i*72 + c*8] = v;
  }

  // ---- transmittance: wave shfl scan + cross-wave prefix ----
  float x = fmaxf(1.0f - alpha, 1e-10f);
  float incl = x;
#pragma unroll
  for (int off = 1; off < 64; off <<= 1){
    float y = __shfl_up(incl, off, 64);
    if (lane >= off) incl *= y;
  }
  float excl = __shfl_up(incl, 1, 64);
  if (lane == 0) excl = 1.0f;
  if (lane == 63) sh_wt[wv] = incl;
  __syncthreads();   // B1: feat visible + wavetot ready

  float pre = 1.0f;
#pragma unroll
  for (int k = 0; k < 4; k++) if (k < wv) pre *= sh_wt[k];
  const float last = sh_wt[0]*sh_wt[1]*sh_wt[2]*sh_wt[3];
  const float av = pre * excl;
  const float w  = alpha * av;
  sh_w[i] = w;

  // per-sample outputs
  float* outw = out + 36864;            // weights      (4096*256)
  float* outa = out + 36864 + 1048576;  // alphainv_cum (4096*257)
  outw[ray*NSAMP + i] = w;
  outa[ray*(NSAMP+1) + i] = av;
  if (i == NSAMP-1) outa[ray*(NSAMP+1) + NSAMP] = last;

  // depth/acc/normals reductions
  {
    float vals[5] = { w*t, w, w*nx, w*ny, w*nz };
#pragma unroll
    for (int v = 0; v < 5; v++){
      float s = vals[v];
#pragma unroll
      for (int m = 32; m > 0; m >>= 1) s += __shfl_xor(s, m, 64);
      if (lane == 0) red[wv][v] = s;
    }
  }
  __syncthreads();   // B2
  if (i == 0){
    float s0 = red[0][0]+red[1][0]+red[2][0]+red[3][0];
    float s1 = red[0][1]+red[1][1]+red[2][1]+red[3][1];
    float s2 = red[0][2]+red[1][2]+red[2][2]+red[3][2];
    float s3 = red[0][3]+red[1][3]+red[2][3]+red[3][3];
    float s4 = red[0][4]+red[1][4]+red[2][4]+red[3][4];
    const float dm = s0 + last * 3.0f;
    float* o1 = out + 12288; o1[ray] = dm;
    float* o2 = out + 16384; o2[ray] = 1.0f / dm;
    float* o3 = out + 20480; o3[ray] = s1;
    float* o4 = out + 24576;
    o4[ray*3+0] = s2; o4[ray*3+1] = s3; o4[ray*3+2] = s4;
  }

  // ---- MLP via MFMA: wave handles rows [wbase, wbase+64) ----
  const short8* fr = (const short8*)((const char*)wb + FRAG_BYTE_OFF);

  // layers 0..2 (K=64 -> N=64)
#pragma unroll
  for (int l = 0; l < 3; l++){
    const int fbase = l * 512;   // in short8 units (4096 ushort / 8)
    f32x4 acc[4][4];
#pragma unroll
    for (int mt = 0; mt < 4; mt++)
#pragma unroll
      for (int nt = 0; nt < 4; nt++) acc[mt][nt] = (f32x4){0.f,0.f,0.f,0.f};

#pragma unroll
    for (int ks = 0; ks < 2; ks++){
      short8 a[4], b[4];
#pragma unroll
      for (int mt = 0; mt < 4; mt++)
        a[mt] = *(const short8*)&act[(wbase + mt*16 + n15)*72 + ks*32 + quad*8];
#pragma unroll
      for (int nt = 0; nt < 4; nt++)
        b[nt] = fr[fbase + (nt*2+ks)*64 + lane];
#pragma unroll
      for (int mt = 0; mt < 4; mt++)
#pragma unroll
        for (int nt = 0; nt < 4; nt++)
          acc[mt][nt] = __builtin_amdgcn_mfma_f32_16x16x32_bf16(a[mt], b[nt], acc[mt][nt], 0, 0, 0);
    }
    __syncthreads();   // reads done before in-place writes
#pragma unroll
    for (int nt = 0; nt < 4; nt++){
      const float bn = wb[OBIAS + l*64 + nt*16 + n15];
#pragma unroll
      for (int mt = 0; mt < 4; mt++){
#pragma unroll
        for (int r = 0; r < 4; r++){
          float vv = fmaxf(acc[mt][nt][r] + bn, 0.0f);
          act[(wbase + mt*16 + quad*4 + r)*72 + nt*16 + n15] = f2bu(vv);
        }
      }
    }
    __syncthreads();   // writes done before next layer reads
  }

  // layer 3 (K=64 -> N=16, 3 valid) + fused weighted rgb reduction
  {
    f32x4 acc3[4];
#pragma unroll
    for (int mt = 0; mt < 4; mt++) acc3[mt] = (f32x4){0.f,0.f,0.f,0.f};
#pragma unroll
    for (int ks = 0; ks < 2; ks++){
      short8 a[4];
#pragma unroll
      for (int mt = 0; mt < 4; mt++)
        a[mt] = *(const short8*)&act[(wbase + mt*16 + n15)*72 + ks*32 + quad*8];
      short8 b = fr[1536 + ks*64 + lane];
#pragma unroll
      for (int mt = 0; mt < 4; mt++)
        acc3[mt] = __builtin_amdgcn_mfma_f32_16x16x32_bf16(a[mt], b, acc3[mt], 0, 0, 0);
    }
    const float bn3 = wb[OBIAS + 208 + n15];
    float p = 0.0f;
#pragma unroll
    for (int mt = 0; mt < 4; mt++){
#pragma unroll
      for (int r = 0; r < 4; r++){
        const float wr = sh_w[wbase + mt*16 + quad*4 + r];
        const float logit = acc3[mt][r] + bn3;
        p += wr * (1.0f / (1.0f + __expf(-logit)));
      }
    }
    p += __shfl_xor(p, 16, 64);
    p += __shfl_xor(p, 32, 64);
    if (lane < 16) red_rgb[wv][lane] = p;
  }
  __syncthreads();   // B3
  if (i < 3){
    float s = red_rgb[0][i] + red_rgb[1][i] + red_rgb[2][i] + red_rgb[3][i];
    out[ray*3+i] = s + last;   // + BG*last, BG=1
  }
}

__global__ __launch_bounds__(256)
void render_kernel(const void* __restrict__ latent, const void* __restrict__ normals,
                   const float* __restrict__ wb, float* __restrict__ out)
{
  if (wb[OFLAG] > 0.5f)
    render_body<float>((const float*)latent, (const float*)normals, wb, out);
  else
    render_body<bf16 >((const bf16*)latent,  (const bf16*)normals,  wb, out);
}

extern "C" void kernel_launch(void* const* d_in, const int* in_sizes, int n_in,
                              void* d_out, int out_size, void* d_ws, size_t ws_size,
                              hipStream_t stream)
{
  float* wb = (float*)d_ws;
  prep<<<1, 256, 0, stream>>>(d_in[5], d_in[6], d_in[7], d_in[8],
                              d_in[9], d_in[10], d_in[11], d_in[12],
                              d_in[0], d_in[1], d_in[2], wb);
  render_kernel<<<NRAYS, 256, 0, stream>>>(d_in[3], d_in[4], wb, (float*)d_out);
}

// Round 5
// 361.982 us; speedup vs baseline: 4.5746x; 1.3259x over previous
//
#include <hip/hip_runtime.h>
#include <hip/hip_bf16.h>
#include <math.h>

typedef __hip_bfloat16 bf16;
typedef float f32x4 __attribute__((ext_vector_type(4)));
typedef short short8 __attribute__((ext_vector_type(8)));

#define NRAYS 4096
#define NSAMP 256
#define RESG  128
#define RS2   16384      // 128*128 (x stride)
#define RS3   2097152    // 128^3   (channel stride)
#define ACT_SHIFT (-4.59511985013459f)

// ---- ws layout ----
// floats:
#define OFLAG 0
#define OBIAS 16        // b0@16, b1@80, b2@144, b3(16 padded)@224
#define ORO   272       // rays_o fp32 [4096*3]
#define ORD   12560     // rays_d normalized
#define OVD   24848     // viewdirs normalized
// bf16 MFMA B-fragments:
#define FRAG_BYTE_OFF 148544
// interleaved grids (fast path):
#define LATIL_BYTE_OFF 1048576ULL            // ushort [128][128][128][16]  (67.1 MB)
#define NRMIL_BYTE_OFF 68157440ULL           // f32x4  [128][128][128]      (33.5 MB)
#define WS_NEED        101711872ULL

__device__ __forceinline__ float ldT(const float* p, size_t i){ return p[i]; }
__device__ __forceinline__ float ldT(const bf16*  p, size_t i){ return __bfloat162float(p[i]); }

// RNE float->bf16 bits
__device__ __forceinline__ unsigned short f2bu(float f){
  unsigned int x = __float_as_uint(f);
  unsigned int r = (x + 0x7FFFu + ((x >> 16) & 1u)) >> 16;
  return (unsigned short)r;
}
__device__ __forceinline__ float bu2f(short s){
  return __uint_as_float(((unsigned int)(unsigned short)s) << 16);
}

template<typename T>
__device__ void fill_ws(const void* W0,const void* b0,const void* W1,const void* b1,
                        const void* W2,const void* b2,const void* W3,const void* b3,
                        const void* ro,const void* rd,const void* vd,
                        float* __restrict__ wb, int tid)
{
  const T* tW0=(const T*)W0; const T* tb0=(const T*)b0;
  const T* tW1=(const T*)W1; const T* tb1=(const T*)b1;
  const T* tW2=(const T*)W2; const T* tb2=(const T*)b2;
  const T* tW3=(const T*)W3; const T* tb3=(const T*)b3;
  const T* tro=(const T*)ro; const T* trd=(const T*)rd; const T* tvd=(const T*)vd;

  for (int idx = tid; idx < 64; idx += 256){
    wb[16+idx]  = ldT(tb0, idx);
    wb[80+idx]  = ldT(tb1, idx);
    wb[144+idx] = ldT(tb2, idx);
  }
  if (tid < 16) wb[224+tid] = (tid < 3) ? ldT(tb3, tid) : 0.0f;

  for (int r = tid; r < NRAYS; r += 256){
    float ox = ldT(tro, r*3+0), oy = ldT(tro, r*3+1), oz = ldT(tro, r*3+2);
    wb[ORO+r*3+0]=ox; wb[ORO+r*3+1]=oy; wb[ORO+r*3+2]=oz;
    float dx = ldT(trd, r*3+0), dy = ldT(trd, r*3+1), dz = ldT(trd, r*3+2);
    float dn = 1.0f / sqrtf(dx*dx+dy*dy+dz*dz);
    wb[ORD+r*3+0]=dx*dn; wb[ORD+r*3+1]=dy*dn; wb[ORD+r*3+2]=dz*dn;
    float vx = ldT(tvd, r*3+0), vy = ldT(tvd, r*3+1), vz = ldT(tvd, r*3+2);
    float vn = 1.0f / sqrtf(vx*vx+vy*vy+vz*vz);
    wb[OVD+r*3+0]=vx*vn; wb[OVD+r*3+1]=vy*vn; wb[OVD+r*3+2]=vz*vn;
  }

  // B-fragments (bf16). mfma_f32_16x16x32_bf16 B layout:
  //   lane holds B[k = ks*32 + (lane>>4)*8 + j][n = nt*16 + (lane&15)]
  unsigned short* fu = (unsigned short*)((char*)wb + FRAG_BYTE_OFF);
  for (int idx = tid; idx < 4096; idx += 256){
    int blk = idx >> 9, rem = idx & 511, lane = rem >> 3, j = rem & 7;
    int nt = blk >> 1, ks = blk & 1;
    int k = ks*32 + ((lane>>4)<<3) + j, n = nt*16 + (lane & 15);
    float v = (k < 54) ? ldT(tW0, k*64 + n) : 0.0f;
    fu[idx] = f2bu(v);
  }
  for (int idx = tid; idx < 4096; idx += 256){
    int blk = idx >> 9, rem = idx & 511, lane = rem >> 3, j = rem & 7;
    int nt = blk >> 1, ks = blk & 1;
    int k = ks*32 + ((lane>>4)<<3) + j, n = nt*16 + (lane & 15);
    fu[4096+idx] = f2bu(ldT(tW1, k*64 + n));
    fu[8192+idx] = f2bu(ldT(tW2, k*64 + n));
  }
  for (int idx = tid; idx < 1024; idx += 256){
    int blk = idx >> 9, rem = idx & 511, lane = rem >> 3, j = rem & 7;
    int ks = blk;
    int k = ks*32 + ((lane>>4)<<3) + j, n = lane & 15;
    float v = (n < 3) ? ldT(tW3, k*3 + n) : 0.0f;
    fu[12288+idx] = f2bu(v);
  }
}

__global__ void prep(const void* W0,const void* b0,const void* W1,const void* b1,
                     const void* W2,const void* b2,const void* W3,const void* b3,
                     const void* ro,const void* rd,const void* vd,
                     float* __restrict__ wb)
{
  __shared__ int s_f32;
  const int tid = threadIdx.x;
  if (tid == 0) s_f32 = 0;
  __syncthreads();
  {
    const bf16* t1 = (const bf16*)W1;
    float a = fabsf(__bfloat162float(t1[2*tid]));
    float b = fabsf(__bfloat162float(t1[2*tid+1]));
    if (!(a < 100.0f) || !(b < 100.0f)) atomicOr(&s_f32, 1);
  }
  __syncthreads();
  const bool isf32 = (s_f32 != 0);
  if (tid == 0) wb[OFLAG] = isf32 ? 1.0f : 0.0f;
  if (isf32) fill_ws<float>(W0,b0,W1,b1,W2,b2,W3,b3,ro,rd,vd,wb,tid);
  else       fill_ws<bf16 >(W0,b0,W1,b1,W2,b2,W3,b3,ro,rd,vd,wb,tid);
}

// ---- grid layout transforms ----
// latent [16][128^3] -> bf16 [128^3][16]; thread handles (voxel, half)
__global__ __launch_bounds__(256)
void interleave_lat(const void* __restrict__ latent, float* __restrict__ wb)
{
  unsigned short* lat_il = (unsigned short*)((char*)wb + LATIL_BYTE_OFF);
  const int T = blockIdx.x*256 + threadIdx.x;   // 0..2^22-1
  const int v = T >> 1, h = T & 1, cb = h*8;
  short8 o;
  if (wb[OFLAG] > 0.5f){
    const float* p = (const float*)latent;
#pragma unroll
    for (int j = 0; j < 8; j++) o[j] = (short)f2bu(p[(size_t)(cb+j)*RS3 + v]);
  } else {
    const unsigned short* p = (const unsigned short*)latent;
#pragma unroll
    for (int j = 0; j < 8; j++) o[j] = (short)p[(size_t)(cb+j)*RS3 + v];
  }
  *(short8*)&lat_il[((size_t)v<<4) + cb] = o;
}

// normals [3][128^3] -> f32x4 [128^3]
__global__ __launch_bounds__(256)
void interleave_nrm(const void* __restrict__ normals, float* __restrict__ wb)
{
  f32x4* nrm_il = (f32x4*)((char*)wb + NRMIL_BYTE_OFF);
  const int v = blockIdx.x*256 + threadIdx.x;   // 0..2^21-1
  f32x4 o;
  if (wb[OFLAG] > 0.5f){
    const float* p = (const float*)normals;
    o[0]=p[v]; o[1]=p[(size_t)RS3+v]; o[2]=p[(size_t)2*RS3+v]; o[3]=0.0f;
  } else {
    const unsigned short* p = (const unsigned short*)normals;
    o[0]=bu2f(p[v]); o[1]=bu2f(p[(size_t)RS3+v]); o[2]=bu2f(p[(size_t)2*RS3+v]); o[3]=0.0f;
  }
  nrm_il[v] = o;
}

// ---- fast render: one block/ray, thread i = sample i, interleaved grids ----
__global__ __launch_bounds__(256, 4)
void render_fast(const float* __restrict__ wb, float* __restrict__ out)
{
  const int ray  = blockIdx.x;
  const int i    = threadIdx.x;
  const int lane = i & 63;
  const int wv   = i >> 6;
  const int quad = lane >> 4;
  const int n15  = lane & 15;
  const int wbase = wv * 64;

  __shared__ unsigned short act[NSAMP*72];   // row stride 72 bf16 (144 B)
  __shared__ float sh_w[NSAMP];
  __shared__ float sh_wt[4];
  __shared__ float red[4][8];
  __shared__ float red_rgb[4][16];

  const unsigned short* lat_il = (const unsigned short*)((const char*)wb + LATIL_BYTE_OFF);
  const f32x4* nrm_il = (const f32x4*)((const char*)wb + NRMIL_BYTE_OFF);

  const float ox = wb[ORO+ray*3+0], oy = wb[ORO+ray*3+1], oz = wb[ORO+ray*3+2];
  const float dx = wb[ORD+ray*3+0], dy = wb[ORD+ray*3+1], dz = wb[ORD+ray*3+2];
  const float vx = wb[OVD+ray*3+0], vy = wb[OVD+ray*3+1], vz = wb[OVD+ray*3+2];

  const float t  = 0.2f + (2.8f/255.0f) * (float)i;
  const float px = ox + dx*t, py = oy + dy*t, pz = oz + dz*t;
  const bool inb = (px >= -1.0f) & (px <= 1.0f) & (py >= -1.0f) & (py <= 1.0f)
                 & (pz >= -1.0f) & (pz <= 1.0f);

  float alpha = 0.0f, nx = 0.0f, ny = 0.0f, nz = 0.0f;
  unsigned short* arow = &act[i*72];

  if (inb) {
    float ux = fminf(fmaxf((px+1.0f)*0.5f, 0.0f), 1.0f) * 127.0f;
    float uy = fminf(fmaxf((py+1.0f)*0.5f, 0.0f), 1.0f) * 127.0f;
    float uz = fminf(fmaxf((pz+1.0f)*0.5f, 0.0f), 1.0f) * 127.0f;
    int x0 = (int)floorf(ux); x0 = x0 > 126 ? 126 : (x0 < 0 ? 0 : x0);
    int y0 = (int)floorf(uy); y0 = y0 > 126 ? 126 : (y0 < 0 ? 0 : y0);
    int z0 = (int)floorf(uz); z0 = z0 > 126 ? 126 : (z0 < 0 ? 0 : z0);
    float fx = ux - (float)x0, fy = uy - (float)y0, fz = uz - (float)z0;
    const float gx = 1.0f - fx, gy = 1.0f - fy, gz = 1.0f - fz;

    const int vb = (x0<<14) + (y0<<7) + z0;
    const unsigned short* Lp = lat_il + ((size_t)vb<<4);
    const f32x4* Np = nrm_il + vb;

    float ch[16];
#pragma unroll
    for (int c = 0; c < 16; c++) ch[c] = 0.0f;
    float nr0 = 0.0f, nr1 = 0.0f, nr2 = 0.0f;

    const int   loff[4] = {0, 1<<18, 1<<11, (1<<18)+(1<<11)};   // ushort offsets
    const int   noff[4] = {0, 16384, 128, 16384+128};           // f32x4 offsets
    const float wxy[4]  = {gx*gy, fx*gy, gx*fy, fx*fy};

#pragma unroll
    for (int cr = 0; cr < 4; cr++){
      const unsigned short* p = Lp + loff[cr];
      short8 a0 = *(const short8*)(p);        // z0, ch0..7
      short8 a1 = *(const short8*)(p+8);      // z0, ch8..15
      short8 b0 = *(const short8*)(p+16);     // z1, ch0..7
      short8 b1 = *(const short8*)(p+24);     // z1, ch8..15
      const float wz0 = wxy[cr]*gz, wz1 = wxy[cr]*fz;
#pragma unroll
      for (int j = 0; j < 8; j++){
        ch[j]   += wz0*bu2f(a0[j]) + wz1*bu2f(b0[j]);
        ch[j+8] += wz0*bu2f(a1[j]) + wz1*bu2f(b1[j]);
      }
      f32x4 n0 = Np[noff[cr]];
      f32x4 n1 = Np[noff[cr]+1];
      nr0 += wz0*n0[0] + wz1*n1[0];
      nr1 += wz0*n0[1] + wz1*n1[1];
      nr2 += wz0*n0[2] + wz1*n1[2];
    }

    float xs = ch[0] + ACT_SHIFT;
    float sp = xs > 15.0f ? xs : log1pf(__expf(xs));
    alpha = 1.0f - __expf(-sp * 0.5f);

    float nn  = sqrtf(nr0*nr0 + nr1*nr1 + nr2*nr2);
    float ninv = 1.0f / fmaxf(nn, 1e-12f);
    nx = nr0*ninv; ny = nr1*ninv; nz = nr2*ninv;

    float dt = -(vx*nx + vy*ny + vz*nz);
    float rx = 2.0f*dt*nx + vx, ry = 2.0f*dt*ny + vy, rz = 2.0f*dt*nz + vz;

    // feat -> LDS in 16-element chunks (keeps VGPR low)
    short8 v0, v1;
    // chunk A: ch1..8 | ch9..15, rx
#pragma unroll
    for (int j = 0; j < 8; j++) v0[j] = (short)f2bu(ch[1+j]);
#pragma unroll
    for (int j = 0; j < 7; j++) v1[j] = (short)f2bu(ch[9+j]);
    v1[7] = (short)f2bu(rx);
    *(short8*)&arow[0] = v0; *(short8*)&arow[8] = v1;
    // chunk B: ry, rz, sin f0..f4(x,y)
    v0[0]=(short)f2bu(ry); v0[1]=(short)f2bu(rz);
    v0[2]=(short)f2bu(__sinf(rx));        v0[3]=(short)f2bu(__sinf(ry));        v0[4]=(short)f2bu(__sinf(rz));
    v0[5]=(short)f2bu(__sinf(rx*2.0f));   v0[6]=(short)f2bu(__sinf(ry*2.0f));   v0[7]=(short)f2bu(__sinf(rz*2.0f));
    v1[0]=(short)f2bu(__sinf(rx*4.0f));   v1[1]=(short)f2bu(__sinf(ry*4.0f));   v1[2]=(short)f2bu(__sinf(rz*4.0f));
    v1[3]=(short)f2bu(__sinf(rx*8.0f));   v1[4]=(short)f2bu(__sinf(ry*8.0f));   v1[5]=(short)f2bu(__sinf(rz*8.0f));
    v1[6]=(short)f2bu(__sinf(rx*16.0f));  v1[7]=(short)f2bu(__sinf(ry*16.0f));
    *(short8*)&arow[16] = v0; *(short8*)&arow[24] = v1;
    // chunk C: sin f4z,f5xyz | cos f0..f3
    v0[0]=(short)f2bu(__sinf(rz*16.0f));  v0[1]=(short)f2bu(__sinf(rx*32.0f));
    v0[2]=(short)f2bu(__sinf(ry*32.0f));  v0[3]=(short)f2bu(__sinf(rz*32.0f));
    v0[4]=(short)f2bu(__cosf(rx));        v0[5]=(short)f2bu(__cosf(ry));        v0[6]=(short)f2bu(__cosf(rz));
    v0[7]=(short)f2bu(__cosf(rx*2.0f));
    v1[0]=(short)f2bu(__cosf(ry*2.0f));   v1[1]=(short)f2bu(__cosf(rz*2.0f));
    v1[2]=(short)f2bu(__cosf(rx*4.0f));   v1[3]=(short)f2bu(__cosf(ry*4.0f));   v1[4]=(short)f2bu(__cosf(rz*4.0f));
    v1[5]=(short)f2bu(__cosf(rx*8.0f));   v1[6]=(short)f2bu(__cosf(ry*8.0f));   v1[7]=(short)f2bu(__cosf(rz*8.0f));
    *(short8*)&arow[32] = v0; *(short8*)&arow[40] = v1;
    // chunk D: cos f4,f5 + zero pad to K=64
    v0[0]=(short)f2bu(__cosf(rx*16.0f));  v0[1]=(short)f2bu(__cosf(ry*16.0f));  v0[2]=(short)f2bu(__cosf(rz*16.0f));
    v0[3]=(short)f2bu(__cosf(rx*32.0f));  v0[4]=(short)f2bu(__cosf(ry*32.0f));  v0[5]=(short)f2bu(__cosf(rz*32.0f));
    v0[6]=0; v0[7]=0;
#pragma unroll
    for (int j = 0; j < 8; j++) v1[j] = 0;
    *(short8*)&arow[48] = v0; *(short8*)&arow[56] = v1;
  } else {
    short8 z;
#pragma unroll
    for (int j = 0; j < 8; j++) z[j] = 0;
#pragma unroll
    for (int c = 0; c < 8; c++) *(short8*)&arow[c*8] = z;
  }

  // ---- transmittance: wave shfl scan + cross-wave prefix ----
  float xv = fmaxf(1.0f - alpha, 1e-10f);
  float incl = xv;
#pragma unroll
  for (int off = 1; off < 64; off <<= 1){
    float y = __shfl_up(incl, off, 64);
    if (lane >= off) incl *= y;
  }
  float excl = __shfl_up(incl, 1, 64);
  if (lane == 0) excl = 1.0f;
  if (lane == 63) sh_wt[wv] = incl;
  __syncthreads();   // B1: feat visible + wave totals ready

  float pre = 1.0f;
#pragma unroll
  for (int k = 0; k < 4; k++) if (k < wv) pre *= sh_wt[k];
  const float last = sh_wt[0]*sh_wt[1]*sh_wt[2]*sh_wt[3];
  const float av = pre * excl;
  const float w  = alpha * av;
  sh_w[i] = w;

  float* outw = out + 36864;            // weights      (4096*256)
  float* outa = out + 36864 + 1048576;  // alphainv_cum (4096*257)
  outw[ray*NSAMP + i] = w;
  outa[ray*(NSAMP+1) + i] = av;
  if (i == NSAMP-1) outa[ray*(NSAMP+1) + NSAMP] = last;

  {
    float vals[5] = { w*t, w, w*nx, w*ny, w*nz };
#pragma unroll
    for (int v = 0; v < 5; v++){
      float s = vals[v];
#pragma unroll
      for (int m = 32; m > 0; m >>= 1) s += __shfl_xor(s, m, 64);
      if (lane == 0) red[wv][v] = s;
    }
  }
  __syncthreads();   // B2
  if (i == 0){
    float s0 = red[0][0]+red[1][0]+red[2][0]+red[3][0];
    float s1 = red[0][1]+red[1][1]+red[2][1]+red[3][1];
    float s2 = red[0][2]+red[1][2]+red[2][2]+red[3][2];
    float s3 = red[0][3]+red[1][3]+red[2][3]+red[3][3];
    float s4 = red[0][4]+red[1][4]+red[2][4]+red[3][4];
    const float dm = s0 + last * 3.0f;
    float* o1 = out + 12288; o1[ray] = dm;
    float* o2 = out + 16384; o2[ray] = 1.0f / dm;
    float* o3 = out + 20480; o3[ray] = s1;
    float* o4 = out + 24576;
    o4[ray*3+0] = s2; o4[ray*3+1] = s3; o4[ray*3+2] = s4;
  }

  // ---- MLP via MFMA: wave handles rows [wbase, wbase+64) ----
  const short8* fr = (const short8*)((const char*)wb + FRAG_BYTE_OFF);

#pragma unroll
  for (int l = 0; l < 3; l++){
    const int fbase = l * 512;
    f32x4 acc[4][4];
#pragma unroll
    for (int mt = 0; mt < 4; mt++)
#pragma unroll
      for (int nt = 0; nt < 4; nt++) acc[mt][nt] = (f32x4){0.f,0.f,0.f,0.f};

#pragma unroll
    for (int ks = 0; ks < 2; ks++){
      short8 a[4], b[4];
#pragma unroll
      for (int mt = 0; mt < 4; mt++)
        a[mt] = *(const short8*)&act[(wbase + mt*16 + n15)*72 + ks*32 + quad*8];
#pragma unroll
      for (int nt = 0; nt < 4; nt++)
        b[nt] = fr[fbase + (nt*2+ks)*64 + lane];
#pragma unroll
      for (int mt = 0; mt < 4; mt++)
#pragma unroll
        for (int nt = 0; nt < 4; nt++)
          acc[mt][nt] = __builtin_amdgcn_mfma_f32_16x16x32_bf16(a[mt], b[nt], acc[mt][nt], 0, 0, 0);
    }
    __syncthreads();
#pragma unroll
    for (int nt = 0; nt < 4; nt++){
      const float bn = wb[OBIAS + l*64 + nt*16 + n15];
#pragma unroll
      for (int mt = 0; mt < 4; mt++){
#pragma unroll
        for (int r = 0; r < 4; r++){
          float vv = fmaxf(acc[mt][nt][r] + bn, 0.0f);
          act[(wbase + mt*16 + quad*4 + r)*72 + nt*16 + n15] = f2bu(vv);
        }
      }
    }
    __syncthreads();
  }

  // layer 3 + fused weighted rgb reduction
  {
    f32x4 acc3[4];
#pragma unroll
    for (int mt = 0; mt < 4; mt++) acc3[mt] = (f32x4){0.f,0.f,0.f,0.f};
#pragma unroll
    for (int ks = 0; ks < 2; ks++){
      short8 a[4];
#pragma unroll
      for (int mt = 0; mt < 4; mt++)
        a[mt] = *(const short8*)&act[(wbase + mt*16 + n15)*72 + ks*32 + quad*8];
      short8 b = fr[1536 + ks*64 + lane];
#pragma unroll
      for (int mt = 0; mt < 4; mt++)
        acc3[mt] = __builtin_amdgcn_mfma_f32_16x16x32_bf16(a[mt], b, acc3[mt], 0, 0, 0);
    }
    const float bn3 = wb[OBIAS + 208 + n15];
    float p = 0.0f;
#pragma unroll
    for (int mt = 0; mt < 4; mt++){
#pragma unroll
      for (int r = 0; r < 4; r++){
        const float wr = sh_w[wbase + mt*16 + quad*4 + r];
        const float logit = acc3[mt][r] + bn3;
        p += wr * (1.0f / (1.0f + __expf(-logit)));
      }
    }
    p += __shfl_xor(p, 16, 64);
    p += __shfl_xor(p, 32, 64);
    if (lane < 16) red_rgb[wv][lane] = p;
  }
  __syncthreads();   // B3
  if (i < 3){
    float s = red_rgb[0][i] + red_rgb[1][i] + red_rgb[2][i] + red_rgb[3][i];
    out[ray*3+i] = s + last;   // + BG*last, BG=1
  }
}

// ================= fallback path (ws too small): round-4 kernel =================
template<typename GT>
__device__ __forceinline__ void render_body(const GT* __restrict__ latent,
                                            const GT* __restrict__ normals,
                                            const float* __restrict__ wb,
                                            float* __restrict__ out)
{
  const int ray  = blockIdx.x;
  const int i    = threadIdx.x;
  const int lane = i & 63;
  const int wv   = i >> 6;
  const int quad = lane >> 4;
  const int n15  = lane & 15;
  const int wbase = wv * 64;

  __shared__ unsigned short act[NSAMP*72];
  __shared__ float sh_w[NSAMP];
  __shared__ float sh_wt[4];
  __shared__ float red[4][8];
  __shared__ float red_rgb[4][16];

  const float ox = wb[ORO+ray*3+0], oy = wb[ORO+ray*3+1], oz = wb[ORO+ray*3+2];
  const float dx = wb[ORD+ray*3+0], dy = wb[ORD+ray*3+1], dz = wb[ORD+ray*3+2];
  const float vx = wb[OVD+ray*3+0], vy = wb[OVD+ray*3+1], vz = wb[OVD+ray*3+2];

  const float t  = 0.2f + (2.8f/255.0f) * (float)i;
  const float px = ox + dx*t, py = oy + dy*t, pz = oz + dz*t;
  const bool inb = (px >= -1.0f) & (px <= 1.0f) & (py >= -1.0f) & (py <= 1.0f)
                 & (pz >= -1.0f) & (pz <= 1.0f);

  float alpha = 0.0f, nx = 0.0f, ny = 0.0f, nz = 0.0f;
  float fv[64];
#pragma unroll
  for (int k = 0; k < 64; k++) fv[k] = 0.0f;

  if (inb) {
    float ux = fminf(fmaxf((px+1.0f)*0.5f, 0.0f), 1.0f) * 127.0f;
    float uy = fminf(fmaxf((py+1.0f)*0.5f, 0.0f), 1.0f) * 127.0f;
    float uz = fminf(fmaxf((pz+1.0f)*0.5f, 0.0f), 1.0f) * 127.0f;
    int x0 = (int)floorf(ux); x0 = x0 > 126 ? 126 : (x0 < 0 ? 0 : x0);
    int y0 = (int)floorf(uy); y0 = y0 > 126 ? 126 : (y0 < 0 ? 0 : y0);
    int z0 = (int)floorf(uz); z0 = z0 > 126 ? 126 : (z0 < 0 ? 0 : z0);
    float fx = ux - (float)x0, fy = uy - (float)y0, fz = uz - (float)z0;
    const int base = x0*RS2 + y0*RESG + z0;
    const float gx = 1.0f - fx, gy = 1.0f - fy, gz = 1.0f - fz;
    const float w000 = gx*gy*gz, w100 = fx*gy*gz, w010 = gx*fy*gz, w001 = gx*gy*fz;
    const float w110 = fx*fy*gz, w101 = fx*gy*fz, w011 = gx*fy*fz, w111 = fx*fy*fz;

    float ch[19];
#pragma unroll
    for (int c = 0; c < 19; c++){
      const GT* g = (c < 16 ? latent + c*RS3 : normals + (c-16)*RS3) + base;
      ch[c] = w000*ldT(g,0)        + w100*ldT(g,RS2)
            + w010*ldT(g,RESG)     + w001*ldT(g,1)
            + w110*ldT(g,RS2+RESG) + w101*ldT(g,RS2+1)
            + w011*ldT(g,RESG+1)   + w111*ldT(g,RS2+RESG+1);
    }

    float xs = ch[0] + ACT_SHIFT;
    float sp = xs > 15.0f ? xs : log1pf(__expf(xs));
    alpha = 1.0f - __expf(-sp * 0.5f);

    float nn  = sqrtf(ch[16]*ch[16] + ch[17]*ch[17] + ch[18]*ch[18]);
    float ninv = 1.0f / fmaxf(nn, 1e-12f);
    nx = ch[16]*ninv; ny = ch[17]*ninv; nz = ch[18]*ninv;

    float dt = -(vx*nx + vy*ny + vz*nz);
    float rx = 2.0f*dt*nx + vx, ry = 2.0f*dt*ny + vy, rz = 2.0f*dt*nz + vz;

#pragma unroll
    for (int k = 0; k < 15; k++) fv[k] = ch[k+1];
    fv[15] = rx; fv[16] = ry; fv[17] = rz;
#pragma unroll
    for (int f = 0; f < 6; f++){
      float s = (float)(1 << f);
      fv[18 + f*3 + 0] = __sinf(rx*s);
      fv[18 + f*3 + 1] = __sinf(ry*s);
      fv[18 + f*3 + 2] = __sinf(rz*s);
      fv[36 + f*3 + 0] = __cosf(rx*s);
      fv[36 + f*3 + 1] = __cosf(ry*s);
      fv[36 + f*3 + 2] = __cosf(rz*s);
    }
  }

#pragma unroll
  for (int c = 0; c < 8; c++){
    short8 v;
#pragma unroll
    for (int k = 0; k < 8; k++) v[k] = (short)f2bu(fv[c*8+k]);
    *(short8*)&act[i*72 + c*8] = v;
  }

  float xvv = fmaxf(1.0f - alpha, 1e-10f);
  float incl = xvv;
#pragma unroll
  for (int off = 1; off < 64; off <<= 1){
    float y = __shfl_up(incl, off, 64);
    if (lane >= off) incl *= y;
  }
  float excl = __shfl_up(incl, 1, 64);
  if (lane == 0) excl = 1.0f;
  if (lane == 63) sh_wt[wv] = incl;
  __syncthreads();

  float pre = 1.0f;
#pragma unroll
  for (int k = 0; k < 4; k++) if (k < wv) pre *= sh_wt[k];
  const float last = sh_wt[0]*sh_wt[1]*sh_wt[2]*sh_wt[3];
  const float av = pre * excl;
  const float w  = alpha * av;
  sh_w[i] = w;

  float* outw = out + 36864;
  float* outa = out + 36864 + 1048576;
  outw[ray*NSAMP + i] = w;
  outa[ray*(NSAMP+1) + i] = av;
  if (i == NSAMP-1) outa[ray*(NSAMP+1) + NSAMP] = last;

  {
    float vals[5] = { w*t, w, w*nx, w*ny, w*nz };
#pragma unroll
    for (int v = 0; v < 5; v++){
      float s = vals[v];
#pragma unroll
      for (int m = 32; m > 0; m >>= 1) s += __shfl_xor(s, m, 64);
      if (lane == 0) red[wv][v] = s;
    }
  }
  __syncthreads();
  if (i == 0){
    float s0 = red[0][0]+red[1][0]+red[2][0]+red[3][0];
    float s1 = red[0][1]+red[1][1]+red[2][1]+red[3][1];
    float s2 = red[0][2]+red[1][2]+red[2][2]+red[3][2];
    float s3 = red[0][3]+red[1][3]+red[2][3]+red[3][3];
    float s4 = red[0][4]+red[1][4]+red[2][4]+red[3][4];
    const float dm = s0 + last * 3.0f;
    float* o1 = out + 12288; o1[ray] = dm;
    float* o2 = out + 16384; o2[ray] = 1.0f / dm;
    float* o3 = out + 20480; o3[ray] = s1;
    float* o4 = out + 24576;
    o4[ray*3+0] = s2; o4[ray*3+1] = s3; o4[ray*3+2] = s4;
  }

  const short8* fr = (const short8*)((const char*)wb + FRAG_BYTE_OFF);

#pragma unroll
  for (int l = 0; l < 3; l++){
    const int fbase = l * 512;
    f32x4 acc[4][4];
#pragma unroll
    for (int mt = 0; mt < 4; mt++)
#pragma unroll
      for (int nt = 0; nt < 4; nt++) acc[mt][nt] = (f32x4){0.f,0.f,0.f,0.f};

#pragma unroll
    for (int ks = 0; ks < 2; ks++){
      short8 a[4], b[4];
#pragma unroll
      for (int mt = 0; mt < 4; mt++)
        a[mt] = *(const short8*)&act[(wbase + mt*16 + n15)*72 + ks*32 + quad*8];
#pragma unroll
      for (int nt = 0; nt < 4; nt++)
        b[nt] = fr[fbase + (nt*2+ks)*64 + lane];
#pragma unroll
      for (int mt = 0; mt < 4; mt++)
#pragma unroll
        for (int nt = 0; nt < 4; nt++)
          acc[mt][nt] = __builtin_amdgcn_mfma_f32_16x16x32_bf16(a[mt], b[nt], acc[mt][nt], 0, 0, 0);
    }
    __syncthreads();
#pragma unroll
    for (int nt = 0; nt < 4; nt++){
      const float bn = wb[OBIAS + l*64 + nt*16 + n15];
#pragma unroll
      for (int mt = 0; mt < 4; mt++){
#pragma unroll
        for (int r = 0; r < 4; r++){
          float vv = fmaxf(acc[mt][nt][r] + bn, 0.0f);
          act[(wbase + mt*16 + quad*4 + r)*72 + nt*16 + n15] = f2bu(vv);
        }
      }
    }
    __syncthreads();
  }

  {
    f32x4 acc3[4];
#pragma unroll
    for (int mt = 0; mt < 4; mt++) acc3[mt] = (f32x4){0.f,0.f,0.f,0.f};
#pragma unroll
    for (int ks = 0; ks < 2; ks++){
      short8 a[4];
#pragma unroll
      for (int mt = 0; mt < 4; mt++)
        a[mt] = *(const short8*)&act[(wbase + mt*16 + n15)*72 + ks*32 + quad*8];
      short8 b = fr[1536 + ks*64 + lane];
#pragma unroll
      for (int mt = 0; mt < 4; mt++)
        acc3[mt] = __builtin_amdgcn_mfma_f32_16x16x32_bf16(a[mt], b, acc3[mt], 0, 0, 0);
    }
    const float bn3 = wb[OBIAS + 208 + n15];
    float p = 0.0f;
#pragma unroll
    for (int mt = 0; mt < 4; mt++){
#pragma unroll
      for (int r = 0; r < 4; r++){
        const float wr = sh_w[wbase + mt*16 + quad*4 + r];
        const float logit = acc3[mt][r] + bn3;
        p += wr * (1.0f / (1.0f + __expf(-logit)));
      }
    }
    p += __shfl_xor(p, 16, 64);
    p += __shfl_xor(p, 32, 64);
    if (lane < 16) red_rgb[wv][lane] = p;
  }
  __syncthreads();
  if (i < 3){
    float s = red_rgb[0][i] + red_rgb[1][i] + red_rgb[2][i] + red_rgb[3][i];
    out[ray*3+i] = s + last;
  }
}

__global__ __launch_bounds__(256)
void render_fallback(const void* __restrict__ latent, const void* __restrict__ normals,
                     const float* __restrict__ wb, float* __restrict__ out)
{
  if (wb[OFLAG] > 0.5f)
    render_body<float>((const float*)latent, (const float*)normals, wb, out);
  else
    render_body<bf16 >((const bf16*)latent,  (const bf16*)normals,  wb, out);
}

extern "C" void kernel_launch(void* const* d_in, const int* in_sizes, int n_in,
                              void* d_out, int out_size, void* d_ws, size_t ws_size,
                              hipStream_t stream)
{
  float* wb = (float*)d_ws;
  prep<<<1, 256, 0, stream>>>(d_in[5], d_in[6], d_in[7], d_in[8],
                              d_in[9], d_in[10], d_in[11], d_in[12],
                              d_in[0], d_in[1], d_in[2], wb);
  if (ws_size >= WS_NEED){
    interleave_lat<<<16384, 256, 0, stream>>>(d_in[3], wb);
    interleave_nrm<<<8192, 256, 0, stream>>>(d_in[4], wb);
    render_fast<<<NRAYS, 256, 0, stream>>>(wb, (float*)d_out);
  } else {
    render_fallback<<<NRAYS, 256, 0, stream>>>(d_in[3], d_in[4], wb, (float*)d_out);
  }
}